// Round 10
// baseline (759.204 us; speedup 1.0000x reference)
//
#include <hip/hip_runtime.h>
#include <stdint.h>

#define TT 16

typedef float v2f __attribute__((ext_vector_type(2)));
typedef unsigned long long u64;

// {1.0f, 1.0f} as a 64-bit constant for the SGPR-pair mask select.
#define ONES2 0x3f8000003f800000ULL

// Locked reference semantics (R7 variant A, verified absmax=0.0 in R9):
//   cur1 = fmaf(x2,w2, fmaf(x1,w1, x0*w0)) + b1          (f32, fma ascending)
//   mem  = fmaf(0.9f, mem, cur) - reset                  (fused recurrence)
//   dots = single-acc ascending-h masked adds, bias added after dot
// Exact rewrites: masked add == fma(m,w,acc), m in {0,1} (acc never -0);
// v_pk_fma_f32 is componentwise IEEE. Mask {m,m} is wave-uniform -> fed as an
// SGPR pair (s_cselect_b64) directly into VOP3P via inline asm, cutting the
// per-t VALU cost to the encoding floor (2 pk-fma = 4 MACs in phase B).
// READLANE LEGALITY: all readlanes + their source defs stay in uniform
// control flow (R8 lesson); only the final store is divergent.
__device__ __forceinline__ float lstep(float mem, float cur) {
    const float reset = (mem > 1.0f) ? 1.0f : 0.0f;
    return __builtin_fmaf(0.9f, mem, cur) - reset;
}

__global__ __launch_bounds__(256, 4) void snn_fast(
    const float* __restrict__ x,     // [B,3]
    const float* __restrict__ W1,    // [3,256]
    const float* __restrict__ b1,    // [256]
    const float* __restrict__ W2,    // [256,256]
    const float* __restrict__ b2,    // [256]
    const float* __restrict__ Wout,  // [25,256,4]
    const float* __restrict__ bout,  // [25,4]
    float* __restrict__ out)         // [B,25,4]
{
#pragma clang fp contract(off)
    const int tid = threadIdx.x;
    const int l   = tid & 63;                 // lane; owns hidden units 4l..4l+3
    const int b   = blockIdx.x * 4 + (tid >> 6);

    // ---------------- Phase A: layer 1 ----------------
    const float x0 = x[b * 3 + 0], x1 = x[b * 3 + 1], x2 = x[b * 3 + 2];
    const float4 w1r0 = ((const float4*)W1)[l];
    const float4 w1r1 = ((const float4*)W1)[64 + l];
    const float4 w1r2 = ((const float4*)W1)[128 + l];
    const float4 b1v  = ((const float4*)b1)[l];

    const float wa0[4] = {w1r0.x, w1r0.y, w1r0.z, w1r0.w};
    const float wa1[4] = {w1r1.x, w1r1.y, w1r1.z, w1r1.w};
    const float wa2[4] = {w1r2.x, w1r2.y, w1r2.z, w1r2.w};
    const float bb1[4] = {b1v.x, b1v.y, b1v.z, b1v.w};

    uint32_t b1r[4];   // spike bits for h = 4l+i (VGPRs, uniform flow)
#pragma unroll
    for (int i = 0; i < 4; ++i) {
        const float cur = fmaf(x2, wa2[i], fmaf(x1, wa1[i], x0 * wa0[i])) + bb1[i];
        float mem = 0.f; uint32_t p = 0;
#pragma unroll
        for (int t = 0; t < TT; ++t) {
            mem = lstep(mem, cur);
            if (mem > 1.0f) p |= (1u << t);
        }
        b1r[i] = p;
    }

    // ------- Phase B: layer 2, t-batched sgpr-mask pk-fma (uniform flow) -----
    v2f acc0[TT], acc1[TT];   // acc0: j=4l,4l+1  acc1: j=4l+2,4l+3
#pragma unroll
    for (int t = 0; t < TT; ++t) { acc0[t] = (v2f)0.f; acc1[t] = (v2f)0.f; }

    const float4* W2v = (const float4*)W2;
    for (int h4 = 0; h4 < 64; ++h4) {
        uint32_t pp[4];
        v2f w01[4], w23[4];
        // pass 1: issue all active loads of this 4-row group back-to-back
#pragma unroll
        for (int c = 0; c < 4; ++c) {
            pp[c] = (uint32_t)__builtin_amdgcn_readlane((int)b1r[c], h4);
            if (pp[c]) {
                const float4 w = W2v[(h4 * 4 + c) * 64 + l];
                w01[c] = v2f{w.x, w.y};
                w23[c] = v2f{w.z, w.w};
            }
        }
        // pass 2: masked accumulate (row c's fmas overlap later rows' loads)
#pragma unroll
        for (int c = 0; c < 4; ++c) {
            const uint32_t p = pp[c];
            if (p) {
#pragma unroll
                for (int t = 0; t < TT; ++t) {
                    const u64 msk = ((p >> t) & 1u) ? ONES2 : 0ULL;  // s_cselect_b64
                    asm("v_pk_fma_f32 %0, %2, %3, %0\n\t"
                        "v_pk_fma_f32 %1, %2, %4, %1"
                        : "+v"(acc0[t]), "+v"(acc1[t])
                        : "s"(msk), "v"(w01[c]), "v"(w23[c]));
                }
            }
        }
    }

    const float4 b2v = ((const float4*)b2)[l];
    const float b2a[4] = {b2v.x, b2v.y, b2v.z, b2v.w};
    uint32_t b2r[4];
#pragma unroll
    for (int i = 0; i < 4; ++i) {
        float mem = 0.f; uint32_t p = 0;
#pragma unroll
        for (int t = 0; t < TT; ++t) {
            const float a = (i < 2) ? ((i == 0) ? acc0[t].x : acc0[t].y)
                                    : ((i == 2) ? acc1[t].x : acc1[t].y);
            const float cur = a + b2a[i];         // dot + bias, bias last
            mem = lstep(mem, cur);
            if (mem > 1.0f) p |= (1u << t);
        }
        b2r[i] = p;
    }

    // ------- Phase C: output layer — ALL 64 lanes run (uniform flow) ---------
    const int oc1 = l;                            // 0..63 (<100)
    const int oc2 = (l < 50) ? (l + 50) : 99;     // clamp lanes 50..63 (dup)
    const int base1 = (oc1 >> 2) * 1024 + (oc1 & 3);
    const int base2 = (oc2 >> 2) * 1024 + (oc2 & 3);

    v2f acco[TT];
#pragma unroll
    for (int t = 0; t < TT; ++t) acco[t] = (v2f)0.f;

    for (int h4 = 0; h4 < 64; ++h4) {
        uint32_t pp[4];
        v2f wv[4];
#pragma unroll
        for (int c = 0; c < 4; ++c) {
            pp[c] = (uint32_t)__builtin_amdgcn_readlane((int)b2r[c], h4);
            if (pp[c]) {
                const int h = h4 * 4 + c;
                wv[c] = v2f{Wout[base1 + h * 4], Wout[base2 + h * 4]};
            }
        }
#pragma unroll
        for (int c = 0; c < 4; ++c) {
            const uint32_t p = pp[c];
            if (p) {
#pragma unroll
                for (int t = 0; t < TT; ++t) {
                    const u64 msk = ((p >> t) & 1u) ? ONES2 : 0ULL;
                    asm("v_pk_fma_f32 %0, %1, %2, %0"
                        : "+v"(acco[t])
                        : "s"(msk), "v"(wv[c]));
                }
            }
        }
    }

    const float bo1 = bout[oc1], bo2 = bout[oc2];
    float memA = 0.f, memB = 0.f;
    int cntA = 0, cntB = 0;
#pragma unroll
    for (int t = 0; t < TT; ++t) {
        const float curA = acco[t].x + bo1;
        const float curB = acco[t].y + bo2;
        memA = lstep(memA, curA);
        memB = lstep(memB, curB);
        if (memA > 1.0f) ++cntA;
        if (memB > 1.0f) ++cntB;
    }
    if (l < 50) {
        out[b * 100 + oc1] = (float)cntA;
        out[b * 100 + oc2] = (float)cntB;
    }
}

extern "C" void kernel_launch(void* const* d_in, const int* in_sizes, int n_in,
                              void* d_out, int out_size, void* d_ws, size_t ws_size,
                              hipStream_t stream) {
    const float* x    = (const float*)d_in[0];
    const float* W1   = (const float*)d_in[1];
    const float* b1   = (const float*)d_in[2];
    const float* W2   = (const float*)d_in[3];
    const float* b2   = (const float*)d_in[4];
    const float* Wout = (const float*)d_in[5];
    const float* bout = (const float*)d_in[6];
    float* out = (float*)d_out;

    const int B = in_sizes[0] / 3;   // 32768
    snn_fast<<<B / 4, 256, 0, stream>>>(x, W1, b1, W2, b2, Wout, bout, out);
}